// Round 3
// baseline (128.846 us; speedup 1.0000x reference)
//
#include <hip/hip_runtime.h>
#include <math.h>

// Problem constants (reference: BATCH=4096, DIM=512, sigma = s*I).
#define NB 4096
#define ND 512
#define WT 64                       // wave-tile: 64x64 output per wave
#define NT (NB / WT)                // 64 tile-rows
#define NWT (NT * (NT + 1) / 2)     // 2080 lower-triangular wave-tiles
#define NBLK (NWT / 4)              // 520 blocks x 4 waves

typedef __bf16 bf16x8 __attribute__((ext_vector_type(8)));
typedef float floatx4 __attribute__((ext_vector_type(4)));

// Kernel 1: cast mu -> bf16 (one wave per row), hq[i] = 0.5*sum(bf16(x)^2),
// zero sumexp (ws is re-poisoned to 0xAA before every timed launch).
__global__ __launch_bounds__(256) void prep_kernel(const float* __restrict__ mu,
                                                   __bf16* __restrict__ mubf,
                                                   float* __restrict__ hq,
                                                   float* __restrict__ sumexp) {
    const int t = threadIdx.x;
    const int wave = t >> 6, lane = t & 63;
    const int row = blockIdx.x * 4 + wave;
    const float4* src = (const float4*)(mu + (size_t)row * ND) + lane * 2;
    const float4 v0 = src[0], v1 = src[1];
    bf16x8 pack;
    pack[0] = (__bf16)v0.x; pack[1] = (__bf16)v0.y;
    pack[2] = (__bf16)v0.z; pack[3] = (__bf16)v0.w;
    pack[4] = (__bf16)v1.x; pack[5] = (__bf16)v1.y;
    pack[6] = (__bf16)v1.z; pack[7] = (__bf16)v1.w;
    ((bf16x8*)(mubf + (size_t)row * ND))[lane] = pack;
    float sq = 0.0f;
    #pragma unroll
    for (int e = 0; e < 8; e++) { float f = (float)pack[e]; sq += f * f; }
    #pragma unroll
    for (int off = 32; off > 0; off >>= 1) sq += __shfl_down(sq, off, 64);
    if (lane == 0) {
        hq[row] = 0.5f * sq;
        sumexp[row] = 0.0f;
    }
}

// Kernel 2: barrier-free symmetric Gram + exp + row/col sum scatter.
// Each WAVE owns one 64x64 lower-triangular tile; A/B fragments are loaded
// DIRECTLY from global (bf16x8 = one 16B dwordx4 per lane) — no LDS, no
// __syncthreads, waves free-run and software-pipeline one k-step ahead.
// expo[i,j] = (G_ij - hq_i - hq_j)/s <= ~0 (max on diag = 0), so plain
// sum-of-exp is safe without an online max. Off-diag tiles also scatter
// their column sums to the mirrored rows (symmetry) — halves MFMA work.
__global__ __launch_bounds__(256) void gram_lse_kernel(const __bf16* __restrict__ mubf,
                                                       const float* __restrict__ hq,
                                                       const float* __restrict__ sigma,
                                                       float* __restrict__ sumexp) {
    const int t = threadIdx.x;
    const int wave = t >> 6;
    const int lane = t & 63;
    const int r16 = lane & 15;
    const int quad = lane >> 4;

    // Decode linear wave id -> lower-triangular (ti >= tj) over 64x64 tiles.
    const int w = blockIdx.x * 4 + wave;
    int ti = (int)((sqrtf(8.0f * (float)w + 1.0f) - 1.0f) * 0.5f);
    while ((ti + 1) * (ti + 2) / 2 <= w) ti++;
    while (ti * (ti + 1) / 2 > w) ti--;
    const int tj = w - ti * (ti + 1) / 2;
    const bool isDiag = (ti == tj);
    const int row0 = ti * WT;
    const int col0 = tj * WT;

    // Fragment base pointers: lane holds 8 contiguous k-elems of one row.
    const __bf16* pa[4];
    const __bf16* pb[4];
    #pragma unroll
    for (int i = 0; i < 4; i++)
        pa[i] = mubf + (size_t)(row0 + i * 16 + r16) * ND + quad * 8;
    #pragma unroll
    for (int j = 0; j < 4; j++)
        pb[j] = mubf + (size_t)(col0 + j * 16 + r16) * ND + quad * 8;

    floatx4 acc[4][4];
    #pragma unroll
    for (int i = 0; i < 4; i++)
        #pragma unroll
        for (int j = 0; j < 4; j++) {
            floatx4 z = {0.f, 0.f, 0.f, 0.f};
            acc[i][j] = z;
        }

    bf16x8 ac[4], bc[4], an[4], bn[4];
    #pragma unroll
    for (int i = 0; i < 4; i++) ac[i] = *(const bf16x8*)pa[i];
    #pragma unroll
    for (int j = 0; j < 4; j++) bc[j] = *(const bf16x8*)pb[j];

    #pragma unroll
    for (int kk = 0; kk < 16; kk++) {
        if (kk < 15) {
            #pragma unroll
            for (int i = 0; i < 4; i++) an[i] = *(const bf16x8*)(pa[i] + (kk + 1) * 32);
            #pragma unroll
            for (int j = 0; j < 4; j++) bn[j] = *(const bf16x8*)(pb[j] + (kk + 1) * 32);
        }
        #pragma unroll
        for (int i = 0; i < 4; i++)
            #pragma unroll
            for (int j = 0; j < 4; j++)
                acc[i][j] = __builtin_amdgcn_mfma_f32_16x16x32_bf16(ac[i], bc[j], acc[i][j], 0, 0, 0);
        #pragma unroll
        for (int i = 0; i < 4; i++) ac[i] = an[i];
        #pragma unroll
        for (int j = 0; j < 4; j++) bc[j] = bn[j];
    }

    // Epilogue. C/D layout (m89-verified): col = lane&15, row = quad*4 + reg.
    const float inv_s = 1.0f / sigma[0];
    float hqc[4];
    #pragma unroll
    for (int j = 0; j < 4; j++) hqc[j] = hq[col0 + j * 16 + r16];

    float cs[4] = {0.f, 0.f, 0.f, 0.f};       // per-lane column partials
    #pragma unroll
    for (int i = 0; i < 4; i++) {
        #pragma unroll
        for (int r = 0; r < 4; r++) {
            const int row = row0 + i * 16 + quad * 4 + r;
            const float hr = hq[row];
            float rs = 0.0f;
            #pragma unroll
            for (int j = 0; j < 4; j++) {
                const float v = __expf((acc[i][j][r] - hr - hqc[j]) * inv_s);
                rs += v;
                cs[j] += v;
            }
            rs += __shfl_xor(rs, 1, 64);
            rs += __shfl_xor(rs, 2, 64);
            rs += __shfl_xor(rs, 4, 64);
            rs += __shfl_xor(rs, 8, 64);
            if (r16 == 0) atomicAdd(&sumexp[row], rs);
        }
    }
    if (!isDiag) {
        // Column sums -> mirrored rows (symmetry). Reduce across quads.
        #pragma unroll
        for (int j = 0; j < 4; j++) {
            float c = cs[j];
            c += __shfl_xor(c, 16, 64);
            c += __shfl_xor(c, 32, 64);
            if (quad == 0) atomicAdd(&sumexp[col0 + j * 16 + r16], c);
        }
    }
}

// Kernel 3: entropy = D/2 + ln(B) + (D/2)ln(2*pi*s) - mean_i log(sumexp_i)
__global__ __launch_bounds__(1024) void finalize_kernel(const float* __restrict__ sumexp,
                                                        const float* __restrict__ sigma,
                                                        float* __restrict__ out) {
    const int t = threadIdx.x;
    float local = 0.0f;
    for (int i = t; i < NB; i += 1024) local += logf(sumexp[i]);
    #pragma unroll
    for (int off = 32; off > 0; off >>= 1) local += __shfl_down(local, off, 64);
    __shared__ float red[16];
    if ((t & 63) == 0) red[t >> 6] = local;
    __syncthreads();
    if (t == 0) {
        double tot = 0.0;
        #pragma unroll
        for (int i = 0; i < 16; i++) tot += (double)red[i];
        const double s = (double)sigma[0];
        const double ent = (double)(ND / 2)
                         + log((double)NB)
                         + (double)(ND / 2) * log(2.0 * M_PI * s)
                         - tot / (double)NB;
        out[0] = (float)ent;
        out[1] = (float)ent;
    }
}

extern "C" void kernel_launch(void* const* d_in, const int* in_sizes, int n_in,
                              void* d_out, int out_size, void* d_ws, size_t ws_size,
                              hipStream_t stream) {
    (void)in_sizes; (void)n_in; (void)out_size; (void)ws_size;
    const float* codewords = (const float*)d_in[1];  // d_in[0] = info (unused)
    const float* sigma     = (const float*)d_in[2];
    float* out = (float*)d_out;

    char* ws = (char*)d_ws;
    __bf16* mubf   = (__bf16*)ws;                                  // 4 MB
    float*  hq     = (float*)(ws + (size_t)NB * ND * 2);           // 16 KB
    float*  sumexp = hq + NB;                                      // 16 KB

    prep_kernel<<<NB / 4, 256, 0, stream>>>(codewords, mubf, hq, sumexp);
    gram_lse_kernel<<<NBLK, 256, 0, stream>>>(mubf, hq, sigma, sumexp);
    finalize_kernel<<<1, 1024, 0, stream>>>(sumexp, sigma, out);
}